// Round 6
// baseline (1479.722 us; speedup 1.0000x reference)
//
#include <hip/hip_runtime.h>

#define N_NODES 100000
#define N_EDGES 1600000
#define D 64
#define NWAVES 16
#define WSTRIDE 68   // 68 mod 32 = 4 -> b128 start banks tile all 32 banks

#define BSHIFT 7                                   // 128 nodes per bucket
#define BNODES (1 << BSHIFT)                       // 128
#define NB ((N_NODES + BNODES - 1) / BNODES)       // 782 buckets
#define PB 128                                     // partition blocks
#define TILE ((N_EDGES + PB - 1) / PB)             // 12500 edges per block
#define TBL (NB * PB)                              // 100096
#define SCAN_BLK 1024
#define SCAN_GRID ((TBL + SCAN_BLK - 1) / SCAN_BLK)  // 98
#define MAXB 4096

// round-to-nearest-even fp32 -> bf16 bits
__device__ __forceinline__ unsigned short f2bf(float f) {
    unsigned u = __float_as_uint(f);
    u = (u + 0x7fffu + ((u >> 16) & 1u)) >> 16;
    return (unsigned short)u;
}

__device__ __forceinline__ float4 bf16x4_to_f4(uint2 v) {
    float4 r;
    r.x = __uint_as_float(v.x << 16);
    r.y = __uint_as_float(v.x & 0xffff0000u);
    r.z = __uint_as_float(v.y << 16);
    r.w = __uint_as_float(v.y & 0xffff0000u);
    return r;
}

// ---------------------------------------------------------------------------
// 0a) Cast x -> bf16 and reduce global absmax(|x|) (uint-bit atomicMax; valid
//     because the values are non-negative).
// ---------------------------------------------------------------------------
__global__ __launch_bounds__(256) void cast_absmax(const float* __restrict__ x,
                                                   unsigned short* __restrict__ xb,
                                                   unsigned* __restrict__ amax) {
    __shared__ float red[4];
    int i = blockIdx.x * blockDim.x + threadIdx.x;
    float m = 0.0f;
    if (i < N_NODES * D / 4) {
        float4 v = ((const float4*)x)[i];
        ushort4 o;
        o.x = f2bf(v.x); o.y = f2bf(v.y); o.z = f2bf(v.z); o.w = f2bf(v.w);
        ((ushort4*)xb)[i] = o;
        m = fmaxf(fmaxf(fabsf(v.x), fabsf(v.y)), fmaxf(fabsf(v.z), fabsf(v.w)));
    }
    for (int off = 32; off >= 1; off >>= 1) m = fmaxf(m, __shfl_xor(m, off, 64));
    if ((threadIdx.x & 63) == 0) red[threadIdx.x >> 6] = m;
    __syncthreads();
    if (threadIdx.x == 0) {
        float mm = fmaxf(fmaxf(red[0], red[1]), fmaxf(red[2], red[3]));
        atomicMax(amax, __float_as_uint(mm));
    }
}

// ---------------------------------------------------------------------------
// 0b) Quantize bf16 table -> biased uint8: q = clamp(rint(v*127/A),-127,127)+128
// ---------------------------------------------------------------------------
__global__ __launch_bounds__(256) void quant8(const unsigned short* __restrict__ inb,
                                              unsigned char* __restrict__ out8,
                                              const unsigned* __restrict__ amax_bits) {
    int i = blockIdx.x * blockDim.x + threadIdx.x;           // dword index
    if (i >= N_NODES * D / 4) return;
    float A = __uint_as_float(*amax_bits);
    float s = (A > 0.0f) ? 127.0f / A : 0.0f;
    uint2 v = ((const uint2*)inb)[i];
    float4 f = bf16x4_to_f4(v);
    int q0 = min(127, max(-127, __float2int_rn(f.x * s))) + 128;
    int q1 = min(127, max(-127, __float2int_rn(f.y * s))) + 128;
    int q2 = min(127, max(-127, __float2int_rn(f.z * s))) + 128;
    int q3 = min(127, max(-127, __float2int_rn(f.w * s))) + 128;
    ((unsigned*)out8)[i] = (unsigned)q0 | ((unsigned)q1 << 8) |
                           ((unsigned)q2 << 16) | ((unsigned)q3 << 24);
}

// ---------------------------------------------------------------------------
// 1) Per-(block,bucket) histogram of dst buckets -> table[bucket][block]
// ---------------------------------------------------------------------------
__global__ __launch_bounds__(1024) void p1_hist(const int* __restrict__ dst,
                                                int* __restrict__ table) {
    __shared__ int hist[NB];
    for (int i = threadIdx.x; i < NB; i += 1024) hist[i] = 0;
    __syncthreads();
    int lo = blockIdx.x * TILE;
    int hi = min(lo + TILE, N_EDGES);
    for (int e = lo + threadIdx.x; e < hi; e += 1024)
        atomicAdd(&hist[dst[e] >> BSHIFT], 1);
    __syncthreads();
    for (int b = threadIdx.x; b < NB; b += 1024)
        table[b * PB + blockIdx.x] = hist[b];
}

// ---------------------------------------------------------------------------
// 2) Exclusive scan of the TBL-entry table
// ---------------------------------------------------------------------------
__global__ __launch_bounds__(SCAN_BLK) void scan_blocks_n(int* __restrict__ buf,
                                                          int* __restrict__ blk_sum,
                                                          int n) {
    __shared__ int tmp[SCAN_BLK];
    int i = blockIdx.x * SCAN_BLK + threadIdx.x;
    int v = (i < n) ? buf[i] : 0;
    int val = v;
    tmp[threadIdx.x] = val;
    __syncthreads();
    for (int off = 1; off < SCAN_BLK; off <<= 1) {
        int t = (threadIdx.x >= off) ? tmp[threadIdx.x - off] : 0;
        __syncthreads();
        val += t;
        tmp[threadIdx.x] = val;
        __syncthreads();
    }
    if (i < n) buf[i] = val - v;
    if (threadIdx.x == SCAN_BLK - 1) blk_sum[blockIdx.x] = val;
}

__global__ __launch_bounds__(128) void scan_partials(const int* __restrict__ blk_sum,
                                                     int* __restrict__ blk_off, int nb) {
    __shared__ int t[128];
    int i = threadIdx.x;
    int v = (i < nb) ? blk_sum[i] : 0;
    int val = v;
    t[i] = val;
    __syncthreads();
    for (int off = 1; off < 128; off <<= 1) {
        int u = (i >= off) ? t[i - off] : 0;
        __syncthreads();
        val += u;
        t[i] = val;
        __syncthreads();
    }
    if (i < nb) blk_off[i] = val - v;
}

__global__ __launch_bounds__(256) void scan_finalize(int* __restrict__ buf,
                                                     const int* __restrict__ blk_off,
                                                     int n) {
    int i = blockIdx.x * 256 + threadIdx.x;
    if (i < n) buf[i] += blk_off[i >> 10];
}

// ---------------------------------------------------------------------------
// 3) Partition scatter: packed (src<<7 | local_dst) into per-(block,bucket) runs
// ---------------------------------------------------------------------------
__global__ __launch_bounds__(1024) void p1_scatter(const int* __restrict__ src,
                                                   const int* __restrict__ dst,
                                                   const int* __restrict__ table,
                                                   int* __restrict__ part) {
    __shared__ int cur[NB];
    for (int b = threadIdx.x; b < NB; b += 1024)
        cur[b] = table[b * PB + blockIdx.x];
    __syncthreads();
    int lo = blockIdx.x * TILE;
    int hi = min(lo + TILE, N_EDGES);
    for (int e = lo + threadIdx.x; e < hi; e += 1024) {
        int dd = dst[e];
        int b = dd >> BSHIFT;
        int p = atomicAdd(&cur[b], 1);
        part[p] = (src[e] << BSHIFT) | (dd & (BNODES - 1));
    }
}

// ---------------------------------------------------------------------------
// 4) Per-bucket sort -> row_ptr + sorted_src
// ---------------------------------------------------------------------------
__global__ __launch_bounds__(1024) void p2_sort(const int* __restrict__ table,
                                                const int* __restrict__ part,
                                                int* __restrict__ row_ptr,
                                                int* __restrict__ sorted_src) {
    __shared__ int in_buf[MAXB];
    __shared__ int out_buf[MAXB];
    __shared__ int hist[BNODES];
    __shared__ int exs[BNODES];
    __shared__ int cursor[BNODES];

    int k = blockIdx.x;
    int base = table[k * PB];
    int end  = (k < NB - 1) ? table[(k + 1) * PB] : N_EDGES;
    int count = end - base;
    int tid = threadIdx.x;

    for (int i = tid; i < BNODES; i += 1024) hist[i] = 0;
    __syncthreads();

    if (count <= MAXB) {
        for (int i = tid; i < count; i += 1024) {
            int w = part[base + i];
            in_buf[i] = w;
            atomicAdd(&hist[w & (BNODES - 1)], 1);
        }
        __syncthreads();
        if (tid < 64) {
            int a = hist[2 * tid], b = hist[2 * tid + 1];
            int s = a + b, incl = s;
            for (int off = 1; off < 64; off <<= 1) {
                int t = __shfl_up(incl, off, 64);
                if (tid >= off) incl += t;
            }
            int excl = incl - s;
            exs[2 * tid] = excl;
            exs[2 * tid + 1] = excl + a;
        }
        __syncthreads();
        if (tid < BNODES) {
            int node = k * BNODES + tid;
            if (node < N_NODES) row_ptr[node] = base + exs[tid];
            cursor[tid] = exs[tid];
        }
        if (tid == 0 && k == NB - 1) row_ptr[N_NODES] = N_EDGES;
        __syncthreads();
        for (int i = tid; i < count; i += 1024) {
            int w = in_buf[i];
            int r = atomicAdd(&cursor[w & (BNODES - 1)], 1);
            out_buf[r] = w >> BSHIFT;
        }
        __syncthreads();
        for (int i = tid; i < count; i += 1024)
            sorted_src[base + i] = out_buf[i];
    } else {
        for (int i = tid; i < count; i += 1024)
            atomicAdd(&hist[part[base + i] & (BNODES - 1)], 1);
        __syncthreads();
        if (tid < 64) {
            int a = hist[2 * tid], b = hist[2 * tid + 1];
            int s = a + b, incl = s;
            for (int off = 1; off < 64; off <<= 1) {
                int t = __shfl_up(incl, off, 64);
                if (tid >= off) incl += t;
            }
            int excl = incl - s;
            exs[2 * tid] = excl;
            exs[2 * tid + 1] = excl + a;
        }
        __syncthreads();
        if (tid < BNODES) {
            int node = k * BNODES + tid;
            if (node < N_NODES) row_ptr[node] = base + exs[tid];
            cursor[tid] = exs[tid];
        }
        if (tid == 0 && k == NB - 1) row_ptr[N_NODES] = N_EDGES;
        __syncthreads();
        for (int i = tid; i < count; i += 1024) {
            int w = part[base + i];
            int r = atomicAdd(&cursor[w & (BNODES - 1)], 1);
            sorted_src[base + r] = w >> BSHIFT;
        }
    }
}

// ---------------------------------------------------------------------------
// 5) Fused SAGE layer, int8 gather.
//    Gather table is biased uint8 (q+128), row = 64 B. Lane (g=lane>>2,
//    c=lane&3) reads uint4 -> 16 rows per wave-instruction. Neighbor sums are
//    exact packed-u16 integer adds (2 masked adds per dword, deg*255 << 65536);
//    dequant once per node: (sum - 128*deg) * A/127 / deg. Self rows bf16.
//    Streaming accesses nontemporal so the int8 table owns the L2.
// ---------------------------------------------------------------------------
__global__ __launch_bounds__(NWAVES * 64) void sage8(
    const int* __restrict__ row_ptr, const int* __restrict__ nbr,
    const uint4* __restrict__ tab8,             // int8 table as uint4 rows (4/row)
    const unsigned short* __restrict__ selfb,   // bf16 self rows
    const unsigned* __restrict__ amax_bits,     // gather-table absmax
    const float* __restrict__ w_l, const float* __restrict__ b_l,
    const float* __restrict__ w_r,
    float* __restrict__ out,
    unsigned short* __restrict__ outb,
    unsigned* __restrict__ amax_out,            // absmax of (relu'd) output, or null
    int apply_relu)
{
    __shared__ float wl_s[D * WSTRIDE];
    __shared__ float wr_s[D * WSTRIDE];
    __shared__ float bias[D];
    __shared__ float mean_s[NWAVES][D];
    __shared__ float x_s[NWAVES][D];

    int tid = threadIdx.x;
    for (int i = tid; i < D * D; i += NWAVES * 64) {
        int o = i >> 6, k = i & 63;
        wl_s[o * WSTRIDE + k] = w_l[i];
        wr_s[o * WSTRIDE + k] = w_r[i];
    }
    if (tid < D) bias[tid] = b_l[tid];
    __syncthreads();

    int wave = tid >> 6;
    int lane = tid & 63;
    int node = blockIdx.x * NWAVES + wave;
    if (node >= N_NODES) return;

    float A  = __uint_as_float(*amax_bits);
    float gs = A * (1.0f / 127.0f);

    int g = lane >> 2;        // neighbor group 0..15
    int c = lane & 3;         // 16-byte chunk of the row

    int begin = row_ptr[node];
    int end   = row_ptr[node + 1];

    unsigned aLo[4] = {0, 0, 0, 0};   // dims 16c+{0,2},{4,6},{8,10},{12,14} in u16 halves
    unsigned aHi[4] = {0, 0, 0, 0};   // dims 16c+{1,3},{5,7},{9,11},{13,15}
    for (int base = begin; base < end; base += 64) {
        int m = end - base; if (m > 64) m = 64;
        int id = (lane < m) ? __builtin_nontemporal_load(&nbr[base + lane]) : 0;
        int j = 0;
        for (; j + 16 <= m; j += 16) {
            int s = __shfl(id, j + g, 64);
            uint4 v = tab8[4 * (size_t)s + c];
            aLo[0] += v.x & 0x00FF00FFu; aHi[0] += (v.x >> 8) & 0x00FF00FFu;
            aLo[1] += v.y & 0x00FF00FFu; aHi[1] += (v.y >> 8) & 0x00FF00FFu;
            aLo[2] += v.z & 0x00FF00FFu; aHi[2] += (v.z >> 8) & 0x00FF00FFu;
            aLo[3] += v.w & 0x00FF00FFu; aHi[3] += (v.w >> 8) & 0x00FF00FFu;
        }
        int rem = m - j;                       // 0..15
        if (rem > 0) {
            int s = __shfl(id, j + g, 64);
            if (g < rem) {
                uint4 v = tab8[4 * (size_t)s + c];
                aLo[0] += v.x & 0x00FF00FFu; aHi[0] += (v.x >> 8) & 0x00FF00FFu;
                aLo[1] += v.y & 0x00FF00FFu; aHi[1] += (v.y >> 8) & 0x00FF00FFu;
                aLo[2] += v.z & 0x00FF00FFu; aHi[2] += (v.z >> 8) & 0x00FF00FFu;
                aLo[3] += v.w & 0x00FF00FFu; aHi[3] += (v.w >> 8) & 0x00FF00FFu;
            }
        }
    }

    // Cross-group integer reduce (no carry across u16 halves: deg*255 < 65536)
#pragma unroll
    for (int off = 4; off <= 32; off <<= 1) {
#pragma unroll
        for (int k = 0; k < 4; ++k) {
            aLo[k] += (unsigned)__shfl_xor((int)aLo[k], off, 64);
            aHi[k] += (unsigned)__shfl_xor((int)aHi[k], off, 64);
        }
    }

    int   deg  = end - begin;
    float invd = 1.0f / fmaxf((float)deg, 1.0f);
    float b128 = 128.0f * (float)deg;
    float sc   = gs * invd;

    if (lane < 4) {                     // lane c writes dims 16c..16c+15
#pragma unroll
        for (int k = 0; k < 4; ++k) {
            float d0 = ((float)(aLo[k] & 0xFFFFu) - b128) * sc;
            float d2 = ((float)(aLo[k] >> 16)     - b128) * sc;
            float d1 = ((float)(aHi[k] & 0xFFFFu) - b128) * sc;
            float d3 = ((float)(aHi[k] >> 16)     - b128) * sc;
            *(float4*)&mean_s[wave][16 * lane + 4 * k] = make_float4(d0, d1, d2, d3);
        }
    }
    if (lane < 16) {                    // self row bf16, 8 B per lane
        uint2 xv;
        xv.x = __builtin_nontemporal_load((const unsigned*)&selfb[(size_t)node * D + 4 * lane]);
        xv.y = __builtin_nontemporal_load((const unsigned*)&selfb[(size_t)node * D + 4 * lane] + 1);
        *(float4*)&x_s[wave][4 * lane] = bf16x4_to_f4(xv);
    }
    // Wave-local LDS write->read ordering via compiler lgkmcnt.

    int o = lane;
    float acc = bias[o];
    const float4* wl4p = (const float4*)&wl_s[o * WSTRIDE];
    const float4* wr4p = (const float4*)&wr_s[o * WSTRIDE];
    const float4* m4p  = (const float4*)&mean_s[wave][0];
    const float4* x4p  = (const float4*)&x_s[wave][0];
#pragma unroll
    for (int kq = 0; kq < 16; ++kq) {
        float4 wl4 = wl4p[kq];
        float4 wr4 = wr4p[kq];
        float4 m4  = m4p[kq];
        float4 xx4 = x4p[kq];
        acc += m4.x * wl4.x + m4.y * wl4.y + m4.z * wl4.z + m4.w * wl4.w;
        acc += xx4.x * wr4.x + xx4.y * wr4.y + xx4.z * wr4.z + xx4.w * wr4.w;
    }
    if (apply_relu) acc = fmaxf(acc, 0.0f);
    if (out)  __builtin_nontemporal_store(acc, &out[(size_t)node * D + o]);
    if (outb) __builtin_nontemporal_store(f2bf(acc), &outb[(size_t)node * D + o]);
    if (amax_out) {                      // relu'd -> acc >= 0
        float wm = acc;
        for (int off = 32; off >= 1; off >>= 1) wm = fmaxf(wm, __shfl_xor(wm, off, 64));
        if (lane == 0) atomicMax(amax_out, __float_as_uint(wm));
    }
}

// ---------------------------------------------------------------------------
// Launch
// ---------------------------------------------------------------------------
extern "C" void kernel_launch(void* const* d_in, const int* in_sizes, int n_in,
                              void* d_out, int out_size, void* d_ws, size_t ws_size,
                              hipStream_t stream) {
    const float* x    = (const float*)d_in[0];
    const int*   ei   = (const int*)d_in[1];   // [2, E]: src = ei, dst = ei + E
    const float* w_l1 = (const float*)d_in[2];
    const float* b_l1 = (const float*)d_in[3];
    const float* w_r1 = (const float*)d_in[4];
    const float* w_l2 = (const float*)d_in[5];
    const float* b_l2 = (const float*)d_in[6];
    const float* w_r2 = (const float*)d_in[7];
    float* out = (float*)d_out;

    const int* src = ei;
    const int* dst = ei + N_EDGES;

    // Workspace (~52 MB). Scales first, 16B-aligned segments throughout.
    unsigned* scales   = (unsigned*)d_ws;                 // 4 uints: [0]=A_x, [1]=A_h
    int* table         = (int*)d_ws + 4;                  // TBL
    int* blk_sum       = table + TBL;                     // 128
    int* blk_off       = blk_sum + 128;                   // 128
    int* row_ptr       = blk_off + 128;                   // N+1 (pad to 100004)
    int* part          = row_ptr + 100004;                // E
    int* sorted_src    = part + N_EDGES;                  // E
    unsigned short* xb = (unsigned short*)(sorted_src + N_EDGES);   // N*D bf16
    unsigned short* hb = xb + (size_t)N_NODES * D;                  // N*D bf16
    unsigned char* x8  = (unsigned char*)(hb + (size_t)N_NODES * D);// N*D u8
    unsigned char* h8  = x8 + (size_t)N_NODES * D;                  // N*D u8

    hipMemsetAsync(scales, 0, 16, stream);

    dim3 b256(256);
    int qgrid = (N_NODES * D / 4 + 255) / 256;
    cast_absmax<<<dim3(qgrid), b256, 0, stream>>>(x, xb, &scales[0]);
    quant8<<<dim3(qgrid), b256, 0, stream>>>(xb, x8, &scales[0]);

    p1_hist<<<dim3(PB), dim3(1024), 0, stream>>>(dst, table);
    scan_blocks_n<<<dim3(SCAN_GRID), dim3(SCAN_BLK), 0, stream>>>(table, blk_sum, TBL);
    scan_partials<<<dim3(1), dim3(128), 0, stream>>>(blk_sum, blk_off, SCAN_GRID);
    scan_finalize<<<dim3((TBL + 255) / 256), b256, 0, stream>>>(table, blk_off, TBL);
    p1_scatter<<<dim3(PB), dim3(1024), 0, stream>>>(src, dst, table, part);
    p2_sort<<<dim3(NB), dim3(1024), 0, stream>>>(table, part, row_ptr, sorted_src);

    dim3 lblk(NWAVES * 64);
    dim3 lgrid((N_NODES + NWAVES - 1) / NWAVES);
    sage8<<<lgrid, lblk, 0, stream>>>(row_ptr, sorted_src, (const uint4*)x8, xb,
                                      &scales[0], w_l1, b_l1, w_r1,
                                      (float*)nullptr, hb, &scales[1], /*relu=*/1);
    quant8<<<dim3(qgrid), b256, 0, stream>>>(hb, h8, &scales[1]);
    sage8<<<lgrid, lblk, 0, stream>>>(row_ptr, sorted_src, (const uint4*)h8, hb,
                                      &scales[1], w_l2, b_l2, w_r2,
                                      out, (unsigned short*)nullptr,
                                      (unsigned*)nullptr, /*relu=*/0);
}

// Round 7
// 463.325 us; speedup vs baseline: 3.1937x; 3.1937x over previous
//
#include <hip/hip_runtime.h>

#define N_NODES 100000
#define N_EDGES 1600000
#define D 64
#define NWAVES 16
#define WSTRIDE 68   // 68 mod 32 = 4 -> b128 start banks tile all 32 banks

#define BSHIFT 7                                   // 128 nodes per bucket
#define BNODES (1 << BSHIFT)                       // 128
#define NB ((N_NODES + BNODES - 1) / BNODES)       // 782 buckets
#define PB 128                                     // partition blocks
#define TILE ((N_EDGES + PB - 1) / PB)             // 12500 edges per block
#define TBL (NB * PB)                              // 100096
#define SCAN_BLK 1024
#define SCAN_GRID ((TBL + SCAN_BLK - 1) / SCAN_BLK)  // 98
#define MAXB 4096

// round-to-nearest-even fp32 -> bf16 bits
__device__ __forceinline__ unsigned short f2bf(float f) {
    unsigned u = __float_as_uint(f);
    u = (u + 0x7fffu + ((u >> 16) & 1u)) >> 16;
    return (unsigned short)u;
}

__device__ __forceinline__ float4 bf16x4_to_f4(uint2 v) {
    float4 r;
    r.x = __uint_as_float(v.x << 16);
    r.y = __uint_as_float(v.x & 0xffff0000u);
    r.z = __uint_as_float(v.y << 16);
    r.w = __uint_as_float(v.y & 0xffff0000u);
    return r;
}

// ---------------------------------------------------------------------------
// 0a) Cast x -> bf16 and reduce global absmax(|x|) (per-block atomicMax,
//     6250 atomics total -- fine).
// ---------------------------------------------------------------------------
__global__ __launch_bounds__(256) void cast_absmax(const float* __restrict__ x,
                                                   unsigned short* __restrict__ xb,
                                                   unsigned* __restrict__ amax) {
    __shared__ float red[4];
    int i = blockIdx.x * blockDim.x + threadIdx.x;
    float m = 0.0f;
    if (i < N_NODES * D / 4) {
        float4 v = ((const float4*)x)[i];
        ushort4 o;
        o.x = f2bf(v.x); o.y = f2bf(v.y); o.z = f2bf(v.z); o.w = f2bf(v.w);
        ((ushort4*)xb)[i] = o;
        m = fmaxf(fmaxf(fabsf(v.x), fabsf(v.y)), fmaxf(fabsf(v.z), fabsf(v.w)));
    }
    for (int off = 32; off >= 1; off >>= 1) m = fmaxf(m, __shfl_xor(m, off, 64));
    if ((threadIdx.x & 63) == 0) red[threadIdx.x >> 6] = m;
    __syncthreads();
    if (threadIdx.x == 0) {
        float mm = fmaxf(fmaxf(red[0], red[1]), fmaxf(red[2], red[3]));
        atomicMax(amax, __float_as_uint(mm));
    }
}

// ---------------------------------------------------------------------------
// 0b) Grid-stride absmax over a bf16 array (values >= 0 after relu, but use
//     fabs anyway). 1024 blocks -> 1024 atomics total.
// ---------------------------------------------------------------------------
__global__ __launch_bounds__(256) void absmax_bf16(const unsigned short* __restrict__ inb,
                                                   unsigned* __restrict__ amax) {
    __shared__ float red[4];
    float m = 0.0f;
    int stride = gridDim.x * 256;
    for (int i = blockIdx.x * 256 + threadIdx.x; i < N_NODES * D / 4; i += stride) {
        uint2 v = ((const uint2*)inb)[i];
        float4 f = bf16x4_to_f4(v);
        m = fmaxf(m, fmaxf(fmaxf(fabsf(f.x), fabsf(f.y)), fmaxf(fabsf(f.z), fabsf(f.w))));
    }
    for (int off = 32; off >= 1; off >>= 1) m = fmaxf(m, __shfl_xor(m, off, 64));
    if ((threadIdx.x & 63) == 0) red[threadIdx.x >> 6] = m;
    __syncthreads();
    if (threadIdx.x == 0) {
        float mm = fmaxf(fmaxf(red[0], red[1]), fmaxf(red[2], red[3]));
        atomicMax(amax, __float_as_uint(mm));
    }
}

// ---------------------------------------------------------------------------
// 0c) Quantize bf16 table -> biased uint8: q = clamp(rint(v*127/A),-127,127)+128
// ---------------------------------------------------------------------------
__global__ __launch_bounds__(256) void quant8(const unsigned short* __restrict__ inb,
                                              unsigned char* __restrict__ out8,
                                              const unsigned* __restrict__ amax_bits) {
    int i = blockIdx.x * blockDim.x + threadIdx.x;           // dword index
    if (i >= N_NODES * D / 4) return;
    float A = __uint_as_float(*amax_bits);
    float s = (A > 0.0f) ? 127.0f / A : 0.0f;
    uint2 v = ((const uint2*)inb)[i];
    float4 f = bf16x4_to_f4(v);
    int q0 = min(127, max(-127, __float2int_rn(f.x * s))) + 128;
    int q1 = min(127, max(-127, __float2int_rn(f.y * s))) + 128;
    int q2 = min(127, max(-127, __float2int_rn(f.z * s))) + 128;
    int q3 = min(127, max(-127, __float2int_rn(f.w * s))) + 128;
    ((unsigned*)out8)[i] = (unsigned)q0 | ((unsigned)q1 << 8) |
                           ((unsigned)q2 << 16) | ((unsigned)q3 << 24);
}

// ---------------------------------------------------------------------------
// 1) Per-(block,bucket) histogram of dst buckets -> table[bucket][block]
// ---------------------------------------------------------------------------
__global__ __launch_bounds__(1024) void p1_hist(const int* __restrict__ dst,
                                                int* __restrict__ table) {
    __shared__ int hist[NB];
    for (int i = threadIdx.x; i < NB; i += 1024) hist[i] = 0;
    __syncthreads();
    int lo = blockIdx.x * TILE;
    int hi = min(lo + TILE, N_EDGES);
    for (int e = lo + threadIdx.x; e < hi; e += 1024)
        atomicAdd(&hist[dst[e] >> BSHIFT], 1);
    __syncthreads();
    for (int b = threadIdx.x; b < NB; b += 1024)
        table[b * PB + blockIdx.x] = hist[b];
}

// ---------------------------------------------------------------------------
// 2) Exclusive scan of the TBL-entry table
// ---------------------------------------------------------------------------
__global__ __launch_bounds__(SCAN_BLK) void scan_blocks_n(int* __restrict__ buf,
                                                          int* __restrict__ blk_sum,
                                                          int n) {
    __shared__ int tmp[SCAN_BLK];
    int i = blockIdx.x * SCAN_BLK + threadIdx.x;
    int v = (i < n) ? buf[i] : 0;
    int val = v;
    tmp[threadIdx.x] = val;
    __syncthreads();
    for (int off = 1; off < SCAN_BLK; off <<= 1) {
        int t = (threadIdx.x >= off) ? tmp[threadIdx.x - off] : 0;
        __syncthreads();
        val += t;
        tmp[threadIdx.x] = val;
        __syncthreads();
    }
    if (i < n) buf[i] = val - v;
    if (threadIdx.x == SCAN_BLK - 1) blk_sum[blockIdx.x] = val;
}

__global__ __launch_bounds__(128) void scan_partials(const int* __restrict__ blk_sum,
                                                     int* __restrict__ blk_off, int nb) {
    __shared__ int t[128];
    int i = threadIdx.x;
    int v = (i < nb) ? blk_sum[i] : 0;
    int val = v;
    t[i] = val;
    __syncthreads();
    for (int off = 1; off < 128; off <<= 1) {
        int u = (i >= off) ? t[i - off] : 0;
        __syncthreads();
        val += u;
        t[i] = val;
        __syncthreads();
    }
    if (i < nb) blk_off[i] = val - v;
}

__global__ __launch_bounds__(256) void scan_finalize(int* __restrict__ buf,
                                                     const int* __restrict__ blk_off,
                                                     int n) {
    int i = blockIdx.x * 256 + threadIdx.x;
    if (i < n) buf[i] += blk_off[i >> 10];
}

// ---------------------------------------------------------------------------
// 3) Partition scatter: packed (src<<7 | local_dst) into per-(block,bucket) runs
// ---------------------------------------------------------------------------
__global__ __launch_bounds__(1024) void p1_scatter(const int* __restrict__ src,
                                                   const int* __restrict__ dst,
                                                   const int* __restrict__ table,
                                                   int* __restrict__ part) {
    __shared__ int cur[NB];
    for (int b = threadIdx.x; b < NB; b += 1024)
        cur[b] = table[b * PB + blockIdx.x];
    __syncthreads();
    int lo = blockIdx.x * TILE;
    int hi = min(lo + TILE, N_EDGES);
    for (int e = lo + threadIdx.x; e < hi; e += 1024) {
        int dd = dst[e];
        int b = dd >> BSHIFT;
        int p = atomicAdd(&cur[b], 1);
        part[p] = (src[e] << BSHIFT) | (dd & (BNODES - 1));
    }
}

// ---------------------------------------------------------------------------
// 4) Per-bucket sort -> row_ptr + sorted_src
// ---------------------------------------------------------------------------
__global__ __launch_bounds__(1024) void p2_sort(const int* __restrict__ table,
                                                const int* __restrict__ part,
                                                int* __restrict__ row_ptr,
                                                int* __restrict__ sorted_src) {
    __shared__ int in_buf[MAXB];
    __shared__ int out_buf[MAXB];
    __shared__ int hist[BNODES];
    __shared__ int exs[BNODES];
    __shared__ int cursor[BNODES];

    int k = blockIdx.x;
    int base = table[k * PB];
    int end  = (k < NB - 1) ? table[(k + 1) * PB] : N_EDGES;
    int count = end - base;
    int tid = threadIdx.x;

    for (int i = tid; i < BNODES; i += 1024) hist[i] = 0;
    __syncthreads();

    if (count <= MAXB) {
        for (int i = tid; i < count; i += 1024) {
            int w = part[base + i];
            in_buf[i] = w;
            atomicAdd(&hist[w & (BNODES - 1)], 1);
        }
        __syncthreads();
        if (tid < 64) {
            int a = hist[2 * tid], b = hist[2 * tid + 1];
            int s = a + b, incl = s;
            for (int off = 1; off < 64; off <<= 1) {
                int t = __shfl_up(incl, off, 64);
                if (tid >= off) incl += t;
            }
            int excl = incl - s;
            exs[2 * tid] = excl;
            exs[2 * tid + 1] = excl + a;
        }
        __syncthreads();
        if (tid < BNODES) {
            int node = k * BNODES + tid;
            if (node < N_NODES) row_ptr[node] = base + exs[tid];
            cursor[tid] = exs[tid];
        }
        if (tid == 0 && k == NB - 1) row_ptr[N_NODES] = N_EDGES;
        __syncthreads();
        for (int i = tid; i < count; i += 1024) {
            int w = in_buf[i];
            int r = atomicAdd(&cursor[w & (BNODES - 1)], 1);
            out_buf[r] = w >> BSHIFT;
        }
        __syncthreads();
        for (int i = tid; i < count; i += 1024)
            sorted_src[base + i] = out_buf[i];
    } else {
        for (int i = tid; i < count; i += 1024)
            atomicAdd(&hist[part[base + i] & (BNODES - 1)], 1);
        __syncthreads();
        if (tid < 64) {
            int a = hist[2 * tid], b = hist[2 * tid + 1];
            int s = a + b, incl = s;
            for (int off = 1; off < 64; off <<= 1) {
                int t = __shfl_up(incl, off, 64);
                if (tid >= off) incl += t;
            }
            int excl = incl - s;
            exs[2 * tid] = excl;
            exs[2 * tid + 1] = excl + a;
        }
        __syncthreads();
        if (tid < BNODES) {
            int node = k * BNODES + tid;
            if (node < N_NODES) row_ptr[node] = base + exs[tid];
            cursor[tid] = exs[tid];
        }
        if (tid == 0 && k == NB - 1) row_ptr[N_NODES] = N_EDGES;
        __syncthreads();
        for (int i = tid; i < count; i += 1024) {
            int w = part[base + i];
            int r = atomicAdd(&cursor[w & (BNODES - 1)], 1);
            sorted_src[base + r] = w >> BSHIFT;
        }
    }
}

// ---------------------------------------------------------------------------
// 5) Fused SAGE layer, int8 gather. NO global atomics (round-6 lesson:
//    100k same-address atomicMax serialized the whole layer, 1151 us).
// ---------------------------------------------------------------------------
__global__ __launch_bounds__(NWAVES * 64) void sage8(
    const int* __restrict__ row_ptr, const int* __restrict__ nbr,
    const uint4* __restrict__ tab8,             // int8 table as uint4 rows (4/row)
    const unsigned short* __restrict__ selfb,   // bf16 self rows
    const unsigned* __restrict__ amax_bits,     // gather-table absmax
    const float* __restrict__ w_l, const float* __restrict__ b_l,
    const float* __restrict__ w_r,
    float* __restrict__ out,
    unsigned short* __restrict__ outb,
    int apply_relu)
{
    __shared__ float wl_s[D * WSTRIDE];
    __shared__ float wr_s[D * WSTRIDE];
    __shared__ float bias[D];
    __shared__ float mean_s[NWAVES][D];
    __shared__ float x_s[NWAVES][D];

    int tid = threadIdx.x;
    for (int i = tid; i < D * D; i += NWAVES * 64) {
        int o = i >> 6, k = i & 63;
        wl_s[o * WSTRIDE + k] = w_l[i];
        wr_s[o * WSTRIDE + k] = w_r[i];
    }
    if (tid < D) bias[tid] = b_l[tid];
    __syncthreads();

    int wave = tid >> 6;
    int lane = tid & 63;
    int node = blockIdx.x * NWAVES + wave;
    if (node >= N_NODES) return;

    float A  = __uint_as_float(*amax_bits);
    float gs = A * (1.0f / 127.0f);

    int g = lane >> 2;        // neighbor group 0..15
    int c = lane & 3;         // 16-byte chunk of the row

    int begin = row_ptr[node];
    int end   = row_ptr[node + 1];

    unsigned aLo[4] = {0, 0, 0, 0};
    unsigned aHi[4] = {0, 0, 0, 0};
    for (int base = begin; base < end; base += 64) {
        int m = end - base; if (m > 64) m = 64;
        int id = (lane < m) ? __builtin_nontemporal_load(&nbr[base + lane]) : 0;
        int j = 0;
        for (; j + 16 <= m; j += 16) {
            int s = __shfl(id, j + g, 64);
            uint4 v = tab8[4 * (size_t)s + c];
            aLo[0] += v.x & 0x00FF00FFu; aHi[0] += (v.x >> 8) & 0x00FF00FFu;
            aLo[1] += v.y & 0x00FF00FFu; aHi[1] += (v.y >> 8) & 0x00FF00FFu;
            aLo[2] += v.z & 0x00FF00FFu; aHi[2] += (v.z >> 8) & 0x00FF00FFu;
            aLo[3] += v.w & 0x00FF00FFu; aHi[3] += (v.w >> 8) & 0x00FF00FFu;
        }
        int rem = m - j;                       // 0..15
        if (rem > 0) {
            int s = __shfl(id, j + g, 64);
            if (g < rem) {
                uint4 v = tab8[4 * (size_t)s + c];
                aLo[0] += v.x & 0x00FF00FFu; aHi[0] += (v.x >> 8) & 0x00FF00FFu;
                aLo[1] += v.y & 0x00FF00FFu; aHi[1] += (v.y >> 8) & 0x00FF00FFu;
                aLo[2] += v.z & 0x00FF00FFu; aHi[2] += (v.z >> 8) & 0x00FF00FFu;
                aLo[3] += v.w & 0x00FF00FFu; aHi[3] += (v.w >> 8) & 0x00FF00FFu;
            }
        }
    }

    // Cross-group integer reduce over lane bits 2..5 (no u16 carry: deg*255 < 65536)
#pragma unroll
    for (int off = 4; off <= 32; off <<= 1) {
#pragma unroll
        for (int k = 0; k < 4; ++k) {
            aLo[k] += (unsigned)__shfl_xor((int)aLo[k], off, 64);
            aHi[k] += (unsigned)__shfl_xor((int)aHi[k], off, 64);
        }
    }

    int   deg  = end - begin;
    float invd = 1.0f / fmaxf((float)deg, 1.0f);
    float b128 = 128.0f * (float)deg;
    float sc   = gs * invd;

    if (lane < 4) {                     // lane c writes dims 16c..16c+15
#pragma unroll
        for (int k = 0; k < 4; ++k) {
            float d0 = ((float)(aLo[k] & 0xFFFFu) - b128) * sc;
            float d2 = ((float)(aLo[k] >> 16)     - b128) * sc;
            float d1 = ((float)(aHi[k] & 0xFFFFu) - b128) * sc;
            float d3 = ((float)(aHi[k] >> 16)     - b128) * sc;
            *(float4*)&mean_s[wave][16 * lane + 4 * k] = make_float4(d0, d1, d2, d3);
        }
    }
    if (lane < 16) {                    // self row bf16, 8 B per lane
        uint2 xv;
        xv.x = __builtin_nontemporal_load((const unsigned*)&selfb[(size_t)node * D + 4 * lane]);
        xv.y = __builtin_nontemporal_load((const unsigned*)&selfb[(size_t)node * D + 4 * lane] + 1);
        *(float4*)&x_s[wave][4 * lane] = bf16x4_to_f4(xv);
    }
    // Wave-local LDS write->read ordering via compiler lgkmcnt.

    int o = lane;
    float acc = bias[o];
    const float4* wl4p = (const float4*)&wl_s[o * WSTRIDE];
    const float4* wr4p = (const float4*)&wr_s[o * WSTRIDE];
    const float4* m4p  = (const float4*)&mean_s[wave][0];
    const float4* x4p  = (const float4*)&x_s[wave][0];
#pragma unroll
    for (int kq = 0; kq < 16; ++kq) {
        float4 wl4 = wl4p[kq];
        float4 wr4 = wr4p[kq];
        float4 m4  = m4p[kq];
        float4 xx4 = x4p[kq];
        acc += m4.x * wl4.x + m4.y * wl4.y + m4.z * wl4.z + m4.w * wl4.w;
        acc += xx4.x * wr4.x + xx4.y * wr4.y + xx4.z * wr4.z + xx4.w * wr4.w;
    }
    if (apply_relu) acc = fmaxf(acc, 0.0f);
    if (out)  __builtin_nontemporal_store(acc, &out[(size_t)node * D + o]);
    if (outb) __builtin_nontemporal_store(f2bf(acc), &outb[(size_t)node * D + o]);
}

// ---------------------------------------------------------------------------
// Launch
// ---------------------------------------------------------------------------
extern "C" void kernel_launch(void* const* d_in, const int* in_sizes, int n_in,
                              void* d_out, int out_size, void* d_ws, size_t ws_size,
                              hipStream_t stream) {
    const float* x    = (const float*)d_in[0];
    const int*   ei   = (const int*)d_in[1];   // [2, E]: src = ei, dst = ei + E
    const float* w_l1 = (const float*)d_in[2];
    const float* b_l1 = (const float*)d_in[3];
    const float* w_r1 = (const float*)d_in[4];
    const float* w_l2 = (const float*)d_in[5];
    const float* b_l2 = (const float*)d_in[6];
    const float* w_r2 = (const float*)d_in[7];
    float* out = (float*)d_out;

    const int* src = ei;
    const int* dst = ei + N_EDGES;

    unsigned* scales   = (unsigned*)d_ws;                 // [0]=A_x, [1]=A_h
    int* table         = (int*)d_ws + 4;                  // TBL
    int* blk_sum       = table + TBL;                     // 128
    int* blk_off       = blk_sum + 128;                   // 128
    int* row_ptr       = blk_off + 128;                   // N+1 (pad to 100004)
    int* part          = row_ptr + 100004;                // E
    int* sorted_src    = part + N_EDGES;                  // E
    unsigned short* xb = (unsigned short*)(sorted_src + N_EDGES);   // N*D bf16
    unsigned short* hb = xb + (size_t)N_NODES * D;                  // N*D bf16
    unsigned char* x8  = (unsigned char*)(hb + (size_t)N_NODES * D);// N*D u8
    unsigned char* h8  = x8 + (size_t)N_NODES * D;                  // N*D u8

    hipMemsetAsync(scales, 0, 16, stream);

    dim3 b256(256);
    int qgrid = (N_NODES * D / 4 + 255) / 256;
    cast_absmax<<<dim3(qgrid), b256, 0, stream>>>(x, xb, &scales[0]);
    quant8<<<dim3(qgrid), b256, 0, stream>>>(xb, x8, &scales[0]);

    p1_hist<<<dim3(PB), dim3(1024), 0, stream>>>(dst, table);
    scan_blocks_n<<<dim3(SCAN_GRID), dim3(SCAN_BLK), 0, stream>>>(table, blk_sum, TBL);
    scan_partials<<<dim3(1), dim3(128), 0, stream>>>(blk_sum, blk_off, SCAN_GRID);
    scan_finalize<<<dim3((TBL + 255) / 256), b256, 0, stream>>>(table, blk_off, TBL);
    p1_scatter<<<dim3(PB), dim3(1024), 0, stream>>>(src, dst, table, part);
    p2_sort<<<dim3(NB), dim3(1024), 0, stream>>>(table, part, row_ptr, sorted_src);

    dim3 lblk(NWAVES * 64);
    dim3 lgrid((N_NODES + NWAVES - 1) / NWAVES);
    sage8<<<lgrid, lblk, 0, stream>>>(row_ptr, sorted_src, (const uint4*)x8, xb,
                                      &scales[0], w_l1, b_l1, w_r1,
                                      (float*)nullptr, hb, /*relu=*/1);
    absmax_bf16<<<dim3(1024), b256, 0, stream>>>(hb, &scales[1]);
    quant8<<<dim3(qgrid), b256, 0, stream>>>(hb, h8, &scales[1]);
    sage8<<<lgrid, lblk, 0, stream>>>(row_ptr, sorted_src, (const uint4*)h8, hb,
                                      &scales[1], w_l2, b_l2, w_r2,
                                      out, (unsigned short*)nullptr, /*relu=*/0);
}

// Round 8
// 382.444 us; speedup vs baseline: 3.8691x; 1.2115x over previous
//
#include <hip/hip_runtime.h>

#define N_NODES 100000
#define N_EDGES 1600000
#define D 64
#define NWAVES 16

#define BSHIFT 7                                   // 128 nodes per bucket
#define BNODES (1 << BSHIFT)                       // 128
#define NB ((N_NODES + BNODES - 1) / BNODES)       // 782 buckets
#define PB 128                                     // partition blocks
#define TILE ((N_EDGES + PB - 1) / PB)             // 12500 edges per block
#define TBL (NB * PB)                              // 100096
#define SCAN_BLK 1024
#define SCAN_GRID ((TBL + SCAN_BLK - 1) / SCAN_BLK)  // 98
#define MAXB 4096

typedef __attribute__((ext_vector_type(8))) short short8;   // 8 bf16 (4 VGPRs)
typedef __attribute__((ext_vector_type(4))) float float4v;  // MFMA acc

// round-to-nearest-even fp32 -> bf16 bits
__device__ __forceinline__ unsigned short f2bf(float f) {
    unsigned u = __float_as_uint(f);
    u = (u + 0x7fffu + ((u >> 16) & 1u)) >> 16;
    return (unsigned short)u;
}
__device__ __forceinline__ unsigned packbf2(float a, float b) {
    return (unsigned)f2bf(a) | ((unsigned)f2bf(b) << 16);
}

__device__ __forceinline__ float4 bf16x4_to_f4(uint2 v) {
    float4 r;
    r.x = __uint_as_float(v.x << 16);
    r.y = __uint_as_float(v.x & 0xffff0000u);
    r.z = __uint_as_float(v.y << 16);
    r.w = __uint_as_float(v.y & 0xffff0000u);
    return r;
}

// ---------------------------------------------------------------------------
// 0a) Cast x -> bf16 + global absmax (per-block atomics only)
// ---------------------------------------------------------------------------
__global__ __launch_bounds__(256) void cast_absmax(const float* __restrict__ x,
                                                   unsigned short* __restrict__ xb,
                                                   unsigned* __restrict__ amax) {
    __shared__ float red[4];
    int i = blockIdx.x * blockDim.x + threadIdx.x;
    float m = 0.0f;
    if (i < N_NODES * D / 4) {
        float4 v = ((const float4*)x)[i];
        ushort4 o;
        o.x = f2bf(v.x); o.y = f2bf(v.y); o.z = f2bf(v.z); o.w = f2bf(v.w);
        ((ushort4*)xb)[i] = o;
        m = fmaxf(fmaxf(fabsf(v.x), fabsf(v.y)), fmaxf(fabsf(v.z), fabsf(v.w)));
    }
    for (int off = 32; off >= 1; off >>= 1) m = fmaxf(m, __shfl_xor(m, off, 64));
    if ((threadIdx.x & 63) == 0) red[threadIdx.x >> 6] = m;
    __syncthreads();
    if (threadIdx.x == 0) {
        float mm = fmaxf(fmaxf(red[0], red[1]), fmaxf(red[2], red[3]));
        atomicMax(amax, __float_as_uint(mm));
    }
}

// ---------------------------------------------------------------------------
// 0b) Grid-stride absmax over bf16 array (1024 block atomics total)
// ---------------------------------------------------------------------------
__global__ __launch_bounds__(256) void absmax_bf16(const unsigned short* __restrict__ inb,
                                                   unsigned* __restrict__ amax) {
    __shared__ float red[4];
    float m = 0.0f;
    int stride = gridDim.x * 256;
    for (int i = blockIdx.x * 256 + threadIdx.x; i < N_NODES * D / 4; i += stride) {
        uint2 v = ((const uint2*)inb)[i];
        float4 f = bf16x4_to_f4(v);
        m = fmaxf(m, fmaxf(fmaxf(fabsf(f.x), fabsf(f.y)), fmaxf(fabsf(f.z), fabsf(f.w))));
    }
    for (int off = 32; off >= 1; off >>= 1) m = fmaxf(m, __shfl_xor(m, off, 64));
    if ((threadIdx.x & 63) == 0) red[threadIdx.x >> 6] = m;
    __syncthreads();
    if (threadIdx.x == 0) {
        float mm = fmaxf(fmaxf(red[0], red[1]), fmaxf(red[2], red[3]));
        atomicMax(amax, __float_as_uint(mm));
    }
}

// ---------------------------------------------------------------------------
// 0c) Quantize bf16 -> biased uint8
// ---------------------------------------------------------------------------
__global__ __launch_bounds__(256) void quant8(const unsigned short* __restrict__ inb,
                                              unsigned char* __restrict__ out8,
                                              const unsigned* __restrict__ amax_bits) {
    int i = blockIdx.x * blockDim.x + threadIdx.x;
    if (i >= N_NODES * D / 4) return;
    float A = __uint_as_float(*amax_bits);
    float s = (A > 0.0f) ? 127.0f / A : 0.0f;
    uint2 v = ((const uint2*)inb)[i];
    float4 f = bf16x4_to_f4(v);
    int q0 = min(127, max(-127, __float2int_rn(f.x * s))) + 128;
    int q1 = min(127, max(-127, __float2int_rn(f.y * s))) + 128;
    int q2 = min(127, max(-127, __float2int_rn(f.z * s))) + 128;
    int q3 = min(127, max(-127, __float2int_rn(f.w * s))) + 128;
    ((unsigned*)out8)[i] = (unsigned)q0 | ((unsigned)q1 << 8) |
                           ((unsigned)q2 << 16) | ((unsigned)q3 << 24);
}

// ---------------------------------------------------------------------------
// 0d) Pack weights: Wb[o][k] bf16, k<64 -> w_l[o][k], k>=64 -> w_r[o][k-64]
// ---------------------------------------------------------------------------
__global__ __launch_bounds__(256) void prep_w(const float* __restrict__ wl,
                                              const float* __restrict__ wr,
                                              unsigned short* __restrict__ wb) {
    int i = blockIdx.x * 256 + threadIdx.x;     // 64*128
    if (i < D * 2 * D) {
        int o = i >> 7, k = i & 127;
        float v = (k < D) ? wl[o * D + k] : wr[o * D + (k - D)];
        wb[i] = f2bf(v);
    }
}

// ---------------------------------------------------------------------------
// 1..4) CSR build (unchanged from round 5)
// ---------------------------------------------------------------------------
__global__ __launch_bounds__(1024) void p1_hist(const int* __restrict__ dst,
                                                int* __restrict__ table) {
    __shared__ int hist[NB];
    for (int i = threadIdx.x; i < NB; i += 1024) hist[i] = 0;
    __syncthreads();
    int lo = blockIdx.x * TILE;
    int hi = min(lo + TILE, N_EDGES);
    for (int e = lo + threadIdx.x; e < hi; e += 1024)
        atomicAdd(&hist[dst[e] >> BSHIFT], 1);
    __syncthreads();
    for (int b = threadIdx.x; b < NB; b += 1024)
        table[b * PB + blockIdx.x] = hist[b];
}

__global__ __launch_bounds__(SCAN_BLK) void scan_blocks_n(int* __restrict__ buf,
                                                          int* __restrict__ blk_sum,
                                                          int n) {
    __shared__ int tmp[SCAN_BLK];
    int i = blockIdx.x * SCAN_BLK + threadIdx.x;
    int v = (i < n) ? buf[i] : 0;
    int val = v;
    tmp[threadIdx.x] = val;
    __syncthreads();
    for (int off = 1; off < SCAN_BLK; off <<= 1) {
        int t = (threadIdx.x >= off) ? tmp[threadIdx.x - off] : 0;
        __syncthreads();
        val += t;
        tmp[threadIdx.x] = val;
        __syncthreads();
    }
    if (i < n) buf[i] = val - v;
    if (threadIdx.x == SCAN_BLK - 1) blk_sum[blockIdx.x] = val;
}

__global__ __launch_bounds__(128) void scan_partials(const int* __restrict__ blk_sum,
                                                     int* __restrict__ blk_off, int nb) {
    __shared__ int t[128];
    int i = threadIdx.x;
    int v = (i < nb) ? blk_sum[i] : 0;
    int val = v;
    t[i] = val;
    __syncthreads();
    for (int off = 1; off < 128; off <<= 1) {
        int u = (i >= off) ? t[i - off] : 0;
        __syncthreads();
        val += u;
        t[i] = val;
        __syncthreads();
    }
    if (i < nb) blk_off[i] = val - v;
}

__global__ __launch_bounds__(256) void scan_finalize(int* __restrict__ buf,
                                                     const int* __restrict__ blk_off,
                                                     int n) {
    int i = blockIdx.x * 256 + threadIdx.x;
    if (i < n) buf[i] += blk_off[i >> 10];
}

__global__ __launch_bounds__(1024) void p1_scatter(const int* __restrict__ src,
                                                   const int* __restrict__ dst,
                                                   const int* __restrict__ table,
                                                   int* __restrict__ part) {
    __shared__ int cur[NB];
    for (int b = threadIdx.x; b < NB; b += 1024)
        cur[b] = table[b * PB + blockIdx.x];
    __syncthreads();
    int lo = blockIdx.x * TILE;
    int hi = min(lo + TILE, N_EDGES);
    for (int e = lo + threadIdx.x; e < hi; e += 1024) {
        int dd = dst[e];
        int b = dd >> BSHIFT;
        int p = atomicAdd(&cur[b], 1);
        part[p] = (src[e] << BSHIFT) | (dd & (BNODES - 1));
    }
}

__global__ __launch_bounds__(1024) void p2_sort(const int* __restrict__ table,
                                                const int* __restrict__ part,
                                                int* __restrict__ row_ptr,
                                                int* __restrict__ sorted_src) {
    __shared__ int in_buf[MAXB];
    __shared__ int out_buf[MAXB];
    __shared__ int hist[BNODES];
    __shared__ int exs[BNODES];
    __shared__ int cursor[BNODES];

    int k = blockIdx.x;
    int base = table[k * PB];
    int end  = (k < NB - 1) ? table[(k + 1) * PB] : N_EDGES;
    int count = end - base;
    int tid = threadIdx.x;

    for (int i = tid; i < BNODES; i += 1024) hist[i] = 0;
    __syncthreads();

    if (count <= MAXB) {
        for (int i = tid; i < count; i += 1024) {
            int w = part[base + i];
            in_buf[i] = w;
            atomicAdd(&hist[w & (BNODES - 1)], 1);
        }
        __syncthreads();
        if (tid < 64) {
            int a = hist[2 * tid], b = hist[2 * tid + 1];
            int s = a + b, incl = s;
            for (int off = 1; off < 64; off <<= 1) {
                int t = __shfl_up(incl, off, 64);
                if (tid >= off) incl += t;
            }
            int excl = incl - s;
            exs[2 * tid] = excl;
            exs[2 * tid + 1] = excl + a;
        }
        __syncthreads();
        if (tid < BNODES) {
            int node = k * BNODES + tid;
            if (node < N_NODES) row_ptr[node] = base + exs[tid];
            cursor[tid] = exs[tid];
        }
        if (tid == 0 && k == NB - 1) row_ptr[N_NODES] = N_EDGES;
        __syncthreads();
        for (int i = tid; i < count; i += 1024) {
            int w = in_buf[i];
            int r = atomicAdd(&cursor[w & (BNODES - 1)], 1);
            out_buf[r] = w >> BSHIFT;
        }
        __syncthreads();
        for (int i = tid; i < count; i += 1024)
            sorted_src[base + i] = out_buf[i];
    } else {
        for (int i = tid; i < count; i += 1024)
            atomicAdd(&hist[part[base + i] & (BNODES - 1)], 1);
        __syncthreads();
        if (tid < 64) {
            int a = hist[2 * tid], b = hist[2 * tid + 1];
            int s = a + b, incl = s;
            for (int off = 1; off < 64; off <<= 1) {
                int t = __shfl_up(incl, off, 64);
                if (tid >= off) incl += t;
            }
            int excl = incl - s;
            exs[2 * tid] = excl;
            exs[2 * tid + 1] = excl + a;
        }
        __syncthreads();
        if (tid < BNODES) {
            int node = k * BNODES + tid;
            if (node < N_NODES) row_ptr[node] = base + exs[tid];
            cursor[tid] = exs[tid];
        }
        if (tid == 0 && k == NB - 1) row_ptr[N_NODES] = N_EDGES;
        __syncthreads();
        for (int i = tid; i < count; i += 1024) {
            int w = part[base + i];
            int r = atomicAdd(&cursor[w & (BNODES - 1)], 1);
            sorted_src[base + r] = w >> BSHIFT;
        }
    }
}

// ---------------------------------------------------------------------------
// 5) Fused SAGE layer: int8 gather (wave-per-node) + block MFMA GEMM.
//    Round-7 lesson: per-node LDS weight re-reads (64 ds_read_b128/node) were
//    the bottleneck (~790 LDS cyc/node). Now: 16 gathered nodes -> A[16x128]
//    bf16 in LDS (mean||x), weights B[128x64] bf16 from global (prepacked),
//    wave 0 does 16 MFMAs per block. Per-node LDS cost ~= gather reduce only.
//    MFMA 16x16x32 layouts (HW-verified per guide):
//      A: lane holds A[m=lane&15][k=quad*8+j]  -> b128 from a_s row m
//      B: lane holds B[k=quad*8+j][n=lane&15]  -> b128 from Wb row o (=n)
//      C: col=lane&15, row=quad*4+reg
// ---------------------------------------------------------------------------
__global__ __launch_bounds__(NWAVES * 64) void sage8(
    const int* __restrict__ row_ptr, const int* __restrict__ nbr,
    const uint4* __restrict__ tab8,             // int8 table as uint4 (4/row)
    const unsigned short* __restrict__ selfb,   // bf16 self rows
    const unsigned* __restrict__ amax_bits,     // gather-table absmax
    const unsigned short* __restrict__ wb,      // packed bf16 weights [64][128]
    const float* __restrict__ b_l,
    float* __restrict__ out,
    unsigned short* __restrict__ outb,
    int apply_relu)
{
    __shared__ unsigned short a_s[16][136];   // [node][k] bf16, row 272 B (pad 16 B)
    __shared__ float bias[D];

    int tid = threadIdx.x;
    if (tid < D) bias[tid] = b_l[tid];

    int wave = tid >> 6;
    int lane = tid & 63;
    int node = blockIdx.x * NWAVES + wave;    // N_NODES = 6250*16, no tail

    float A  = __uint_as_float(*amax_bits);
    float gs = A * (1.0f / 127.0f);

    int g = lane >> 2;        // neighbor group 0..15
    int c = lane & 3;         // 16-byte chunk of the int8 row

    int begin = row_ptr[node];
    int end   = row_ptr[node + 1];

    unsigned aLo[4] = {0, 0, 0, 0};
    unsigned aHi[4] = {0, 0, 0, 0};
    for (int base = begin; base < end; base += 64) {
        int m = end - base; if (m > 64) m = 64;
        int id = (lane < m) ? __builtin_nontemporal_load(&nbr[base + lane]) : 0;
        int j = 0;
        for (; j + 16 <= m; j += 16) {
            int s = __shfl(id, j + g, 64);
            uint4 v = tab8[4 * (size_t)s + c];
            aLo[0] += v.x & 0x00FF00FFu; aHi[0] += (v.x >> 8) & 0x00FF00FFu;
            aLo[1] += v.y & 0x00FF00FFu; aHi[1] += (v.y >> 8) & 0x00FF00FFu;
            aLo[2] += v.z & 0x00FF00FFu; aHi[2] += (v.z >> 8) & 0x00FF00FFu;
            aLo[3] += v.w & 0x00FF00FFu; aHi[3] += (v.w >> 8) & 0x00FF00FFu;
        }
        int rem = m - j;
        if (rem > 0) {
            int s = __shfl(id, j + g, 64);
            if (g < rem) {
                uint4 v = tab8[4 * (size_t)s + c];
                aLo[0] += v.x & 0x00FF00FFu; aHi[0] += (v.x >> 8) & 0x00FF00FFu;
                aLo[1] += v.y & 0x00FF00FFu; aHi[1] += (v.y >> 8) & 0x00FF00FFu;
                aLo[2] += v.z & 0x00FF00FFu; aHi[2] += (v.z >> 8) & 0x00FF00FFu;
                aLo[3] += v.w & 0x00FF00FFu; aHi[3] += (v.w >> 8) & 0x00FF00FFu;
            }
        }
    }

    // Cross-group integer reduce (no u16 carry: deg*255 < 65536)
#pragma unroll
    for (int off = 4; off <= 32; off <<= 1) {
#pragma unroll
        for (int k = 0; k < 4; ++k) {
            aLo[k] += (unsigned)__shfl_xor((int)aLo[k], off, 64);
            aHi[k] += (unsigned)__shfl_xor((int)aHi[k], off, 64);
        }
    }

    int   deg  = end - begin;
    float invd = 1.0f / fmaxf((float)deg, 1.0f);
    float b128 = 128.0f * (float)deg;
    float sc   = gs * invd;

    if (lane < 4) {                     // lane c: mean dims 16c..16c+15 -> bf16
        uint4 q0, q1;
        {
            float d0 = ((float)(aLo[0] & 0xFFFFu) - b128) * sc;
            float d2 = ((float)(aLo[0] >> 16)     - b128) * sc;
            float d1 = ((float)(aHi[0] & 0xFFFFu) - b128) * sc;
            float d3 = ((float)(aHi[0] >> 16)     - b128) * sc;
            q0.x = packbf2(d0, d1); q0.y = packbf2(d2, d3);
            d0 = ((float)(aLo[1] & 0xFFFFu) - b128) * sc;
            d2 = ((float)(aLo[1] >> 16)     - b128) * sc;
            d1 = ((float)(aHi[1] & 0xFFFFu) - b128) * sc;
            d3 = ((float)(aHi[1] >> 16)     - b128) * sc;
            q0.z = packbf2(d0, d1); q0.w = packbf2(d2, d3);
            d0 = ((float)(aLo[2] & 0xFFFFu) - b128) * sc;
            d2 = ((float)(aLo[2] >> 16)     - b128) * sc;
            d1 = ((float)(aHi[2] & 0xFFFFu) - b128) * sc;
            d3 = ((float)(aHi[2] >> 16)     - b128) * sc;
            q1.x = packbf2(d0, d1); q1.y = packbf2(d2, d3);
            d0 = ((float)(aLo[3] & 0xFFFFu) - b128) * sc;
            d2 = ((float)(aLo[3] >> 16)     - b128) * sc;
            d1 = ((float)(aHi[3] & 0xFFFFu) - b128) * sc;
            d3 = ((float)(aHi[3] >> 16)     - b128) * sc;
            q1.z = packbf2(d0, d1); q1.w = packbf2(d2, d3);
        }
        *(uint4*)&a_s[wave][16 * lane]     = q0;
        *(uint4*)&a_s[wave][16 * lane + 8] = q1;
    }
    if (lane < 16) {                    // self row bf16 -> A k=64..127
        uint2 xv = *(const uint2*)&selfb[(size_t)node * D + 4 * lane];
        *(uint2*)&a_s[wave][64 + 4 * lane] = xv;
    }
    __syncthreads();

    if (wave != 0) return;

    // ---- Phase 2 (wave 0): C[16x64] = A[16x128] x B[128x64] via 16 MFMAs ----
    int quad = lane >> 4;
    int cc   = lane & 15;

    float4v acc0 = {0.f, 0.f, 0.f, 0.f};
    float4v acc1 = {0.f, 0.f, 0.f, 0.f};
    float4v acc2 = {0.f, 0.f, 0.f, 0.f};
    float4v acc3 = {0.f, 0.f, 0.f, 0.f};

#pragma unroll
    for (int kk = 0; kk < 4; ++kk) {
        short8 af = *(const short8*)&a_s[cc][kk * 32 + quad * 8];
        const unsigned short* wrow = wb + kk * 32 + quad * 8;
        short8 b0 = *(const short8*)(wrow + (size_t)(cc)      * 128);
        short8 b1 = *(const short8*)(wrow + (size_t)(cc + 16) * 128);
        short8 b2 = *(const short8*)(wrow + (size_t)(cc + 32) * 128);
        short8 b3 = *(const short8*)(wrow + (size_t)(cc + 48) * 128);
        acc0 = __builtin_amdgcn_mfma_f32_16x16x32_bf16(af, b0, acc0, 0, 0, 0);
        acc1 = __builtin_amdgcn_mfma_f32_16x16x32_bf16(af, b1, acc1, 0, 0, 0);
        acc2 = __builtin_amdgcn_mfma_f32_16x16x32_bf16(af, b2, acc2, 0, 0, 0);
        acc3 = __builtin_amdgcn_mfma_f32_16x16x32_bf16(af, b3, acc3, 0, 0, 0);
    }

#pragma unroll
    for (int nn = 0; nn < 4; ++nn) {
        float4v af = (nn == 0) ? acc0 : (nn == 1) ? acc1 : (nn == 2) ? acc2 : acc3;
        int o = nn * 16 + cc;
        float bv = bias[o];
#pragma unroll
        for (int r = 0; r < 4; ++r) {
            int nd = blockIdx.x * NWAVES + quad * 4 + r;
            float v = af[r] + bv;
            if (apply_relu) v = fmaxf(v, 0.0f);
            if (out)  __builtin_nontemporal_store(v, &out[(size_t)nd * D + o]);
            if (outb) __builtin_nontemporal_store(f2bf(v), &outb[(size_t)nd * D + o]);
        }
    }
}

// ---------------------------------------------------------------------------
// Launch
// ---------------------------------------------------------------------------
extern "C" void kernel_launch(void* const* d_in, const int* in_sizes, int n_in,
                              void* d_out, int out_size, void* d_ws, size_t ws_size,
                              hipStream_t stream) {
    const float* x    = (const float*)d_in[0];
    const int*   ei   = (const int*)d_in[1];   // [2, E]: src = ei, dst = ei + E
    const float* w_l1 = (const float*)d_in[2];
    const float* b_l1 = (const float*)d_in[3];
    const float* w_r1 = (const float*)d_in[4];
    const float* w_l2 = (const float*)d_in[5];
    const float* b_l2 = (const float*)d_in[6];
    const float* w_r2 = (const float*)d_in[7];
    float* out = (float*)d_out;

    const int* src = ei;
    const int* dst = ei + N_EDGES;

    unsigned* scales   = (unsigned*)d_ws;                 // [0]=A_x, [1]=A_h
    int* table         = (int*)d_ws + 4;                  // TBL
    int* blk_sum       = table + TBL;                     // 128
    int* blk_off       = blk_sum + 128;                   // 128
    int* row_ptr       = blk_off + 128;                   // N+1 (pad 100004)
    int* part          = row_ptr + 100004;                // E
    int* sorted_src    = part + N_EDGES;                  // E
    unsigned short* xb = (unsigned short*)(sorted_src + N_EDGES);   // N*D bf16
    unsigned short* hb = xb + (size_t)N_NODES * D;                  // N*D bf16
    unsigned char* x8  = (unsigned char*)(hb + (size_t)N_NODES * D);// N*D u8
    unsigned char* h8  = x8 + (size_t)N_NODES * D;                  // N*D u8
    unsigned short* wb1 = (unsigned short*)(h8 + (size_t)N_NODES * D); // 64*128
    unsigned short* wb2 = wb1 + D * 2 * D;                             // 64*128

    hipMemsetAsync(scales, 0, 16, stream);

    dim3 b256(256);
    int qgrid = (N_NODES * D / 4 + 255) / 256;
    cast_absmax<<<dim3(qgrid), b256, 0, stream>>>(x, xb, &scales[0]);
    quant8<<<dim3(qgrid), b256, 0, stream>>>(xb, x8, &scales[0]);
    prep_w<<<dim3(32), b256, 0, stream>>>(w_l1, w_r1, wb1);
    prep_w<<<dim3(32), b256, 0, stream>>>(w_l2, w_r2, wb2);

    p1_hist<<<dim3(PB), dim3(1024), 0, stream>>>(dst, table);
    scan_blocks_n<<<dim3(SCAN_GRID), dim3(SCAN_BLK), 0, stream>>>(table, blk_sum, TBL);
    scan_partials<<<dim3(1), dim3(128), 0, stream>>>(blk_sum, blk_off, SCAN_GRID);
    scan_finalize<<<dim3((TBL + 255) / 256), b256, 0, stream>>>(table, blk_off, TBL);
    p1_scatter<<<dim3(PB), dim3(1024), 0, stream>>>(src, dst, table, part);
    p2_sort<<<dim3(NB), dim3(1024), 0, stream>>>(table, part, row_ptr, sorted_src);

    dim3 lblk(NWAVES * 64);
    dim3 lgrid(N_NODES / NWAVES);            // 6250, exact
    sage8<<<lgrid, lblk, 0, stream>>>(row_ptr, sorted_src, (const uint4*)x8, xb,
                                      &scales[0], wb1, b_l1,
                                      (float*)nullptr, hb, /*relu=*/1);
    absmax_bf16<<<dim3(1024), b256, 0, stream>>>(hb, &scales[1]);
    quant8<<<dim3(qgrid), b256, 0, stream>>>(hb, h8, &scales[1]);
    sage8<<<lgrid, lblk, 0, stream>>>(row_ptr, sorted_src, (const uint4*)h8, hb,
                                      &scales[1], wb2, b_l2,
                                      out, (unsigned short*)nullptr, /*relu=*/0);
}

// Round 9
// 317.796 us; speedup vs baseline: 4.6562x; 1.2034x over previous
//
#include <hip/hip_runtime.h>

#define N_NODES 100000
#define N_EDGES 1600000
#define D 64

#define BSHIFT 7                                   // 128 nodes per bucket
#define BNODES (1 << BSHIFT)                       // 128
#define NB ((N_NODES + BNODES - 1) / BNODES)       // 782 buckets
#define PB 256                                     // partition blocks (1 per CU)
#define TILE ((N_EDGES + PB - 1) / PB)             // 6250 edges per block
#define TBL (NB * PB)                              // 200192
#define SCAN_BLK 1024
#define SCAN_GRID ((TBL + SCAN_BLK - 1) / SCAN_BLK)  // 196
#define MAXB 4096

typedef __attribute__((ext_vector_type(8))) short short8;   // 8 bf16 (4 VGPRs)
typedef __attribute__((ext_vector_type(4))) float float4v;  // MFMA acc

// round-to-nearest-even fp32 -> bf16 bits
__device__ __forceinline__ unsigned short f2bf(float f) {
    unsigned u = __float_as_uint(f);
    u = (u + 0x7fffu + ((u >> 16) & 1u)) >> 16;
    return (unsigned short)u;
}
__device__ __forceinline__ unsigned packbf2(float a, float b) {
    return (unsigned)f2bf(a) | ((unsigned)f2bf(b) << 16);
}

__device__ __forceinline__ float4 bf16x4_to_f4(uint2 v) {
    float4 r;
    r.x = __uint_as_float(v.x << 16);
    r.y = __uint_as_float(v.x & 0xffff0000u);
    r.z = __uint_as_float(v.y << 16);
    r.w = __uint_as_float(v.y & 0xffff0000u);
    return r;
}

// ---------------------------------------------------------------------------
// 0a) Cast x -> bf16 + global absmax (per-block atomics only)
// ---------------------------------------------------------------------------
__global__ __launch_bounds__(256) void cast_absmax(const float* __restrict__ x,
                                                   unsigned short* __restrict__ xb,
                                                   unsigned* __restrict__ amax) {
    __shared__ float red[4];
    int i = blockIdx.x * blockDim.x + threadIdx.x;
    float m = 0.0f;
    if (i < N_NODES * D / 4) {
        float4 v = ((const float4*)x)[i];
        ushort4 o;
        o.x = f2bf(v.x); o.y = f2bf(v.y); o.z = f2bf(v.z); o.w = f2bf(v.w);
        ((ushort4*)xb)[i] = o;
        m = fmaxf(fmaxf(fabsf(v.x), fabsf(v.y)), fmaxf(fabsf(v.z), fabsf(v.w)));
    }
    for (int off = 32; off >= 1; off >>= 1) m = fmaxf(m, __shfl_xor(m, off, 64));
    if ((threadIdx.x & 63) == 0) red[threadIdx.x >> 6] = m;
    __syncthreads();
    if (threadIdx.x == 0) {
        float mm = fmaxf(fmaxf(red[0], red[1]), fmaxf(red[2], red[3]));
        atomicMax(amax, __float_as_uint(mm));
    }
}

// ---------------------------------------------------------------------------
// 0b) Grid-stride absmax over bf16 array (1024 block atomics total)
// ---------------------------------------------------------------------------
__global__ __launch_bounds__(256) void absmax_bf16(const unsigned short* __restrict__ inb,
                                                   unsigned* __restrict__ amax) {
    __shared__ float red[4];
    float m = 0.0f;
    int stride = gridDim.x * 256;
    for (int i = blockIdx.x * 256 + threadIdx.x; i < N_NODES * D / 4; i += stride) {
        uint2 v = ((const uint2*)inb)[i];
        float4 f = bf16x4_to_f4(v);
        m = fmaxf(m, fmaxf(fmaxf(fabsf(f.x), fabsf(f.y)), fmaxf(fabsf(f.z), fabsf(f.w))));
    }
    for (int off = 32; off >= 1; off >>= 1) m = fmaxf(m, __shfl_xor(m, off, 64));
    if ((threadIdx.x & 63) == 0) red[threadIdx.x >> 6] = m;
    __syncthreads();
    if (threadIdx.x == 0) {
        float mm = fmaxf(fmaxf(red[0], red[1]), fmaxf(red[2], red[3]));
        atomicMax(amax, __float_as_uint(mm));
    }
}

// ---------------------------------------------------------------------------
// 0c) Quantize bf16 -> biased uint8
// ---------------------------------------------------------------------------
__global__ __launch_bounds__(256) void quant8(const unsigned short* __restrict__ inb,
                                              unsigned char* __restrict__ out8,
                                              const unsigned* __restrict__ amax_bits) {
    int i = blockIdx.x * blockDim.x + threadIdx.x;
    if (i >= N_NODES * D / 4) return;
    float A = __uint_as_float(*amax_bits);
    float s = (A > 0.0f) ? 127.0f / A : 0.0f;
    uint2 v = ((const uint2*)inb)[i];
    float4 f = bf16x4_to_f4(v);
    int q0 = min(127, max(-127, __float2int_rn(f.x * s))) + 128;
    int q1 = min(127, max(-127, __float2int_rn(f.y * s))) + 128;
    int q2 = min(127, max(-127, __float2int_rn(f.z * s))) + 128;
    int q3 = min(127, max(-127, __float2int_rn(f.w * s))) + 128;
    ((unsigned*)out8)[i] = (unsigned)q0 | ((unsigned)q1 << 8) |
                           ((unsigned)q2 << 16) | ((unsigned)q3 << 24);
}

// ---------------------------------------------------------------------------
// 0d) Pack weights: Wb[o][k] bf16, k<64 -> w_l[o][k], k>=64 -> w_r[o][k-64]
// ---------------------------------------------------------------------------
__global__ __launch_bounds__(256) void prep_w(const float* __restrict__ wl,
                                              const float* __restrict__ wr,
                                              unsigned short* __restrict__ wb) {
    int i = blockIdx.x * 256 + threadIdx.x;     // 64*128
    if (i < D * 2 * D) {
        int o = i >> 7, k = i & 127;
        float v = (k < D) ? wl[o * D + k] : wr[o * D + (k - D)];
        wb[i] = f2bf(v);
    }
}

// ---------------------------------------------------------------------------
// 1) Per-(block,bucket) histogram of dst buckets -> table[bucket][block]
// ---------------------------------------------------------------------------
__global__ __launch_bounds__(1024) void p1_hist(const int* __restrict__ dst,
                                                int* __restrict__ table) {
    __shared__ int hist[NB];
    for (int i = threadIdx.x; i < NB; i += 1024) hist[i] = 0;
    __syncthreads();
    int lo = blockIdx.x * TILE;
    int hi = min(lo + TILE, N_EDGES);
    for (int e = lo + threadIdx.x; e < hi; e += 1024)
        atomicAdd(&hist[dst[e] >> BSHIFT], 1);
    __syncthreads();
    for (int b = threadIdx.x; b < NB; b += 1024)
        table[b * PB + blockIdx.x] = hist[b];
}

// ---------------------------------------------------------------------------
// 2) Exclusive scan of the TBL-entry table
// ---------------------------------------------------------------------------
__global__ __launch_bounds__(SCAN_BLK) void scan_blocks_n(int* __restrict__ buf,
                                                          int* __restrict__ blk_sum,
                                                          int n) {
    __shared__ int tmp[SCAN_BLK];
    int i = blockIdx.x * SCAN_BLK + threadIdx.x;
    int v = (i < n) ? buf[i] : 0;
    int val = v;
    tmp[threadIdx.x] = val;
    __syncthreads();
    for (int off = 1; off < SCAN_BLK; off <<= 1) {
        int t = (threadIdx.x >= off) ? tmp[threadIdx.x - off] : 0;
        __syncthreads();
        val += t;
        tmp[threadIdx.x] = val;
        __syncthreads();
    }
    if (i < n) buf[i] = val - v;
    if (threadIdx.x == SCAN_BLK - 1) blk_sum[blockIdx.x] = val;
}

__global__ __launch_bounds__(256) void scan_partials(const int* __restrict__ blk_sum,
                                                     int* __restrict__ blk_off, int nb) {
    __shared__ int t[256];
    int i = threadIdx.x;
    int v = (i < nb) ? blk_sum[i] : 0;
    int val = v;
    t[i] = val;
    __syncthreads();
    for (int off = 1; off < 256; off <<= 1) {
        int u = (i >= off) ? t[i - off] : 0;
        __syncthreads();
        val += u;
        t[i] = val;
        __syncthreads();
    }
    if (i < nb) blk_off[i] = val - v;
}

__global__ __launch_bounds__(256) void scan_finalize(int* __restrict__ buf,
                                                     const int* __restrict__ blk_off,
                                                     int n) {
    int i = blockIdx.x * 256 + threadIdx.x;
    if (i < n) buf[i] += blk_off[i >> 10];
}

// ---------------------------------------------------------------------------
// 3) Partition scatter: packed (src<<7 | local_dst) into per-(block,bucket) runs
// ---------------------------------------------------------------------------
__global__ __launch_bounds__(1024) void p1_scatter(const int* __restrict__ src,
                                                   const int* __restrict__ dst,
                                                   const int* __restrict__ table,
                                                   int* __restrict__ part) {
    __shared__ int cur[NB];
    for (int b = threadIdx.x; b < NB; b += 1024)
        cur[b] = table[b * PB + blockIdx.x];
    __syncthreads();
    int lo = blockIdx.x * TILE;
    int hi = min(lo + TILE, N_EDGES);
    for (int e = lo + threadIdx.x; e < hi; e += 1024) {
        int dd = dst[e];
        int b = dd >> BSHIFT;
        int p = atomicAdd(&cur[b], 1);
        part[p] = (src[e] << BSHIFT) | (dd & (BNODES - 1));
    }
}

// ---------------------------------------------------------------------------
// 4) Per-bucket sort -> row_ptr + sorted_src
// ---------------------------------------------------------------------------
__global__ __launch_bounds__(1024) void p2_sort(const int* __restrict__ table,
                                                const int* __restrict__ part,
                                                int* __restrict__ row_ptr,
                                                int* __restrict__ sorted_src) {
    __shared__ int in_buf[MAXB];
    __shared__ int out_buf[MAXB];
    __shared__ int hist[BNODES];
    __shared__ int exs[BNODES];
    __shared__ int cursor[BNODES];

    int k = blockIdx.x;
    int base = table[k * PB];
    int end  = (k < NB - 1) ? table[(k + 1) * PB] : N_EDGES;
    int count = end - base;
    int tid = threadIdx.x;

    for (int i = tid; i < BNODES; i += 1024) hist[i] = 0;
    __syncthreads();

    if (count <= MAXB) {
        for (int i = tid; i < count; i += 1024) {
            int w = part[base + i];
            in_buf[i] = w;
            atomicAdd(&hist[w & (BNODES - 1)], 1);
        }
        __syncthreads();
        if (tid < 64) {
            int a = hist[2 * tid], b = hist[2 * tid + 1];
            int s = a + b, incl = s;
            for (int off = 1; off < 64; off <<= 1) {
                int t = __shfl_up(incl, off, 64);
                if (tid >= off) incl += t;
            }
            int excl = incl - s;
            exs[2 * tid] = excl;
            exs[2 * tid + 1] = excl + a;
        }
        __syncthreads();
        if (tid < BNODES) {
            int node = k * BNODES + tid;
            if (node < N_NODES) row_ptr[node] = base + exs[tid];
            cursor[tid] = exs[tid];
        }
        if (tid == 0 && k == NB - 1) row_ptr[N_NODES] = N_EDGES;
        __syncthreads();
        for (int i = tid; i < count; i += 1024) {
            int w = in_buf[i];
            int r = atomicAdd(&cursor[w & (BNODES - 1)], 1);
            out_buf[r] = w >> BSHIFT;
        }
        __syncthreads();
        for (int i = tid; i < count; i += 1024)
            sorted_src[base + i] = out_buf[i];
    } else {
        for (int i = tid; i < count; i += 1024)
            atomicAdd(&hist[part[base + i] & (BNODES - 1)], 1);
        __syncthreads();
        if (tid < 64) {
            int a = hist[2 * tid], b = hist[2 * tid + 1];
            int s = a + b, incl = s;
            for (int off = 1; off < 64; off <<= 1) {
                int t = __shfl_up(incl, off, 64);
                if (tid >= off) incl += t;
            }
            int excl = incl - s;
            exs[2 * tid] = excl;
            exs[2 * tid + 1] = excl + a;
        }
        __syncthreads();
        if (tid < BNODES) {
            int node = k * BNODES + tid;
            if (node < N_NODES) row_ptr[node] = base + exs[tid];
            cursor[tid] = exs[tid];
        }
        if (tid == 0 && k == NB - 1) row_ptr[N_NODES] = N_EDGES;
        __syncthreads();
        for (int i = tid; i < count; i += 1024) {
            int w = part[base + i];
            int r = atomicAdd(&cursor[w & (BNODES - 1)], 1);
            sorted_src[base + r] = w >> BSHIFT;
        }
    }
}

// ---------------------------------------------------------------------------
// 5) Fused SAGE layer v2: 2 nodes per wave (32 lanes each), 8 waves = 16
//    nodes per block; int8 gather with packed-u16 exact accumulation; MFMA
//    GEMM spread over waves 0..3 (16 output cols each).
//    Round-8 lesson: wave-per-node wasted fixed overhead (reduce, dequant,
//    remainder) once per node, and max-of-16 degree skew stalled the barrier.
// ---------------------------------------------------------------------------
__global__ __launch_bounds__(512) void sage8(
    const int* __restrict__ row_ptr, const int* __restrict__ nbr,
    const uint4* __restrict__ tab8,             // int8 table as uint4 (4/row)
    const unsigned short* __restrict__ selfb,   // bf16 self rows
    const unsigned* __restrict__ amax_bits,     // gather-table absmax
    const unsigned short* __restrict__ wb,      // packed bf16 weights [64][128]
    const float* __restrict__ b_l,
    float* __restrict__ out,
    unsigned short* __restrict__ outb,
    int apply_relu)
{
    __shared__ unsigned short a_s[16][136];   // [node][k] bf16 (row 272 B)
    __shared__ float bias[D];

    int tid = threadIdx.x;
    if (tid < D) bias[tid] = b_l[tid];

    int wave = tid >> 6;          // 0..7
    int lane = tid & 63;
    int nsel = lane >> 5;         // which of the wave's 2 nodes
    int l32  = lane & 31;
    int g    = l32 >> 2;          // neighbor group 0..7
    int c    = l32 & 3;           // 16-byte chunk of the int8 row
    int arow = wave * 2 + nsel;   // 0..15
    int node = blockIdx.x * 16 + arow;   // N_NODES = 6250*16, no tail

    float A  = __uint_as_float(*amax_bits);
    float gs = A * (1.0f / 127.0f);

    int begin = row_ptr[node];
    int end   = row_ptr[node + 1];

    unsigned aLo[4] = {0, 0, 0, 0};
    unsigned aHi[4] = {0, 0, 0, 0};
    for (int base = begin; base < end; base += 32) {
        int m = end - base; if (m > 32) m = 32;
        int id = (l32 < m) ? __builtin_nontemporal_load(&nbr[base + l32]) : 0;
#pragma unroll
        for (int j = 0; j < 32; j += 8) {
            int s = __shfl(id, nsel * 32 + j + g, 64);   // within own half
            if (j + g < m) {
                uint4 v = tab8[4 * (size_t)s + c];
                aLo[0] += v.x & 0x00FF00FFu; aHi[0] += (v.x >> 8) & 0x00FF00FFu;
                aLo[1] += v.y & 0x00FF00FFu; aHi[1] += (v.y >> 8) & 0x00FF00FFu;
                aLo[2] += v.z & 0x00FF00FFu; aHi[2] += (v.z >> 8) & 0x00FF00FFu;
                aLo[3] += v.w & 0x00FF00FFu; aHi[3] += (v.w >> 8) & 0x00FF00FFu;
            }
        }
    }

    // Reduce across the 8 groups (offsets 4,8,16 -- stays within the 32-lane
    // half). No u16 carry: deg*255 < 65536.
#pragma unroll
    for (int off = 4; off <= 16; off <<= 1) {
#pragma unroll
        for (int k = 0; k < 4; ++k) {
            aLo[k] += (unsigned)__shfl_xor((int)aLo[k], off, 64);
            aHi[k] += (unsigned)__shfl_xor((int)aHi[k], off, 64);
        }
    }

    int   deg  = end - begin;
    float invd = 1.0f / fmaxf((float)deg, 1.0f);
    float bofs = 128.0f * (float)deg;
    float sc   = gs * invd;

    if (l32 < 4) {                  // chunk c = l32: mean dims 16c..16c+15 -> bf16
        uint4 q0, q1;
        float d0 = ((float)(aLo[0] & 0xFFFFu) - bofs) * sc;
        float d2 = ((float)(aLo[0] >> 16)     - bofs) * sc;
        float d1 = ((float)(aHi[0] & 0xFFFFu) - bofs) * sc;
        float d3 = ((float)(aHi[0] >> 16)     - bofs) * sc;
        q0.x = packbf2(d0, d1); q0.y = packbf2(d2, d3);
        d0 = ((float)(aLo[1] & 0xFFFFu) - bofs) * sc;
        d2 = ((float)(aLo[1] >> 16)     - bofs) * sc;
        d1 = ((float)(aHi[1] & 0xFFFFu) - bofs) * sc;
        d3 = ((float)(aHi[1] >> 16)     - bofs) * sc;
        q0.z = packbf2(d0, d1); q0.w = packbf2(d2, d3);
        d0 = ((float)(aLo[2] & 0xFFFFu) - bofs) * sc;
        d2 = ((float)(aLo[2] >> 16)     - bofs) * sc;
        d1 = ((float)(aHi[2] & 0xFFFFu) - bofs) * sc;
        d3 = ((float)(aHi[2] >> 16)     - bofs) * sc;
        q1.x = packbf2(d0, d1); q1.y = packbf2(d2, d3);
        d0 = ((float)(aLo[3] & 0xFFFFu) - bofs) * sc;
        d2 = ((float)(aLo[3] >> 16)     - bofs) * sc;
        d1 = ((float)(aHi[3] & 0xFFFFu) - bofs) * sc;
        d3 = ((float)(aHi[3] >> 16)     - bofs) * sc;
        q1.z = packbf2(d0, d1); q1.w = packbf2(d2, d3);
        *(uint4*)&a_s[arow][16 * l32]     = q0;
        *(uint4*)&a_s[arow][16 * l32 + 8] = q1;
    }
    if (l32 < 16) {                 // self row bf16 -> A k=64..127
        uint2 xv = *(const uint2*)&selfb[(size_t)node * D + 4 * l32];
        *(uint2*)&a_s[arow][64 + 4 * l32] = xv;
    }
    __syncthreads();

    if (wave >= 4) return;

    // ---- MFMA: wave w handles output cols 16w..16w+15 (4 MFMAs each) ----
    // A: lane holds A[m=lane&15][k=quad*8+j]; B: B[k][n=lane&15] = Wb row n;
    // C: col=lane&15, row=quad*4+reg.
    int quad = lane >> 4;
    int cc   = lane & 15;

    float4v acc = {0.f, 0.f, 0.f, 0.f};
#pragma unroll
    for (int kk = 0; kk < 4; ++kk) {
        short8 af = *(const short8*)&a_s[cc][kk * 32 + quad * 8];
        short8 bf = *(const short8*)(wb + (size_t)(wave * 16 + cc) * 128 + kk * 32 + quad * 8);
        acc = __builtin_amdgcn_mfma_f32_16x16x32_bf16(af, bf, acc, 0, 0, 0);
    }

    int o = wave * 16 + cc;
    float bv = bias[o];
#pragma unroll
    for (int r = 0; r < 4; ++r) {
        int nd = blockIdx.x * 16 + quad * 4 + r;
        float v = acc[r] + bv;
        if (apply_relu) v = fmaxf(v, 0.0f);
        if (out)  __builtin_nontemporal_store(v, &out[(size_t)nd * D + o]);
        if (outb) __builtin_nontemporal_store(f2bf(v), &outb[(size_t)nd * D + o]);
    }
}

// ---------------------------------------------------------------------------
// Launch
// ---------------------------------------------------------------------------
extern "C" void kernel_launch(void* const* d_in, const int* in_sizes, int n_in,
                              void* d_out, int out_size, void* d_ws, size_t ws_size,
                              hipStream_t stream) {
    const float* x    = (const float*)d_in[0];
    const int*   ei   = (const int*)d_in[1];   // [2, E]: src = ei, dst = ei + E
    const float* w_l1 = (const float*)d_in[2];
    const float* b_l1 = (const float*)d_in[3];
    const float* w_r1 = (const float*)d_in[4];
    const float* w_l2 = (const float*)d_in[5];
    const float* b_l2 = (const float*)d_in[6];
    const float* w_r2 = (const float*)d_in[7];
    float* out = (float*)d_out;

    const int* src = ei;
    const int* dst = ei + N_EDGES;

    unsigned* scales   = (unsigned*)d_ws;                 // [0]=A_x, [1]=A_h
    int* table         = (int*)d_ws + 4;                  // TBL (200192)
    int* blk_sum       = table + TBL;                     // 256
    int* blk_off       = blk_sum + 256;                   // 256
    int* row_ptr       = blk_off + 256;                   // N+1 (pad 100004)
    int* part          = row_ptr + 100004;                // E
    int* sorted_src    = part + N_EDGES;                  // E
    unsigned short* xb = (unsigned short*)(sorted_src + N_EDGES);   // N*D bf16
    unsigned short* hb = xb + (size_t)N_NODES * D;                  // N*D bf16
    unsigned char* x8  = (unsigned char*)(hb + (size_t)N_NODES * D);// N*D u8
    unsigned char* h8  = x8 + (size_t)N_NODES * D;                  // N*D u8
    unsigned short* wb1 = (unsigned short*)(h8 + (size_t)N_NODES * D); // 64*128
    unsigned short* wb2 = wb1 + D * 2 * D;                             // 64*128

    hipMemsetAsync(scales, 0, 16, stream);

    dim3 b256(256);
    int qgrid = (N_NODES * D / 4 + 255) / 256;
    cast_absmax<<<dim3(qgrid), b256, 0, stream>>>(x, xb, &scales[0]);
    quant8<<<dim3(qgrid), b256, 0, stream>>>(xb, x8, &scales[0]);
    prep_w<<<dim3(32), b256, 0, stream>>>(w_l1, w_r1, wb1);
    prep_w<<<dim3(32), b256, 0, stream>>>(w_l2, w_r2, wb2);

    p1_hist<<<dim3(PB), dim3(1024), 0, stream>>>(dst, table);
    scan_blocks_n<<<dim3(SCAN_GRID), dim3(SCAN_BLK), 0, stream>>>(table, blk_sum, TBL);
    scan_partials<<<dim3(1), dim3(256), 0, stream>>>(blk_sum, blk_off, SCAN_GRID);
    scan_finalize<<<dim3((TBL + 255) / 256), b256, 0, stream>>>(table, blk_off, TBL);
    p1_scatter<<<dim3(PB), dim3(1024), 0, stream>>>(src, dst, table, part);
    p2_sort<<<dim3(NB), dim3(1024), 0, stream>>>(table, part, row_ptr, sorted_src);

    dim3 lblk(512);
    dim3 lgrid(N_NODES / 16);                // 6250, exact
    sage8<<<lgrid, lblk, 0, stream>>>(row_ptr, sorted_src, (const uint4*)x8, xb,
                                      &scales[0], wb1, b_l1,
                                      (float*)nullptr, hb, /*relu=*/1);
    absmax_bf16<<<dim3(1024), b256, 0, stream>>>(hb, &scales[1]);
    quant8<<<dim3(qgrid), b256, 0, stream>>>(hb, h8, &scales[1]);
    sage8<<<lgrid, lblk, 0, stream>>>(row_ptr, sorted_src, (const uint4*)h8, hb,
                                      &scales[1], wb2, b_l2,
                                      out, (unsigned short*)nullptr, /*relu=*/0);
}